// Round 14
// baseline (235.909 us; speedup 1.0000x reference)
//
#include <hip/hip_runtime.h>
#include <hip/hip_bf16.h>

typedef unsigned short u16;
typedef unsigned int u32;
typedef __attribute__((ext_vector_type(8))) unsigned short u16x8;
typedef __attribute__((ext_vector_type(8))) short s16x8;
typedef __attribute__((ext_vector_type(4))) float f32x4;
typedef __attribute__((ext_vector_type(16))) float f32x16;

#define NB 2
#define NLQ 2048
#define NLKV 4096
#define ND 1024
#define NH 16
#define NHD 64
#define SCALE 0.125f
#define QSC (SCALE * 1.44269504f)  // fold scale+log2e into Q

// async global->LDS, 16B per lane; dest = uniform base + lane*16
#define GL16(g, l)                                                            \
    __builtin_amdgcn_global_load_lds(                                         \
        (const __attribute__((address_space(1))) void*)(g),                   \
        (__attribute__((address_space(3))) void*)(l), 16, 0, 0)

__device__ __forceinline__ u16 f2bf(float f) {
    __hip_bfloat16 h = __float2bfloat16(f);
    return *(u16*)&h;
}

__device__ __forceinline__ float fast_exp2(float x) {
    float r;
    asm("v_exp_f32 %0, %1" : "=v"(r) : "v"(x));
    return r;
}

__device__ __forceinline__ u32 pkbf(float lo, float hi_) {
    u32 r;
    asm("v_cvt_pk_bf16_f32 %0, %1, %2" : "=v"(r) : "v"(lo), "v"(hi_));
    return r;
}

// vdst.hi32lanes <-> vsrc.lo32lanes
__device__ __forceinline__ void pl32swap(u32& a, u32& b) {
    asm("v_permlane32_swap_b32 %0, %1" : "+v"(a), "+v"(b));
}

// ---------- fused f32 -> bf16 for x_q and x_kv (one launch) ----------
__global__ __launch_bounds__(256) void cvt2_kernel(const float* __restrict__ xq,
                                                   const float* __restrict__ xkv,
                                                   u16* __restrict__ oq,
                                                   u16* __restrict__ okv) {
    int bid = blockIdx.x;
    const float* in;
    u16* out;
    int i0;
    if (bid < 2048) { in = xq; out = oq; i0 = bid; }
    else { in = xkv; out = okv; i0 = bid - 2048; }
    int i = i0 * 256 + threadIdx.x;
    const float4* p = (const float4*)in;
    float4 a = p[2 * i], b = p[2 * i + 1];
    u16x8 o;
    o[0] = f2bf(a.x); o[1] = f2bf(a.y); o[2] = f2bf(a.z); o[3] = f2bf(a.w);
    o[4] = f2bf(b.x); o[5] = f2bf(b.y); o[6] = f2bf(b.z); o[7] = f2bf(b.w);
    ((u16x8*)out)[i] = o;
}

// ---------- mask int32 -> bf16 {0,1} ----------
__global__ __launch_bounds__(256) void mbf_kernel(const int* __restrict__ mask,
                                                  u16* __restrict__ mbf) {
    int g = blockIdx.x * 256 + threadIdx.x;
    mbf[g] = mask[g] ? 0x3F80 : 0;  // bf16 1.0
}

// ---------- W[k][n] f32 -> Wt[n][k] bf16, 4 weights ----------
__global__ __launch_bounds__(256) void tcvt_kernel(
    const float* __restrict__ w0, const float* __restrict__ w1,
    const float* __restrict__ w2, const float* __restrict__ w3,
    u16* __restrict__ o0, u16* __restrict__ o1,
    u16* __restrict__ o2, u16* __restrict__ o3) {
    const float* w = blockIdx.z == 0 ? w0 : blockIdx.z == 1 ? w1 : blockIdx.z == 2 ? w2 : w3;
    u16* o = blockIdx.z == 0 ? o0 : blockIdx.z == 1 ? o1 : blockIdx.z == 2 ? o2 : o3;
    __shared__ float t[32][33];
    int n0 = blockIdx.x * 32, k0 = blockIdx.y * 32;
    int tx = threadIdx.x, ty = threadIdx.y;
#pragma unroll
    for (int i = 0; i < 4; i++) t[ty + 8 * i][tx] = w[(k0 + ty + 8 * i) * ND + n0 + tx];
    __syncthreads();
#pragma unroll
    for (int i = 0; i < 4; i++) o[(n0 + ty + 8 * i) * ND + k0 + tx] = f2bf(t[tx][ty + 8 * i]);
}

// ---------- unified QKV projection GEMM: 1280 blocks (256 Q + 1024 KV) ----------
// XCD-bijective swizzle (1280 = 8*160). tile 128x128, BK=32, 8 waves 2x4, GL16.
// V-half blocks swap MFMA operands -> D^T in acc -> coalesced V^T store.
__global__ __launch_bounds__(512) void qkv_kernel(
    const u16* __restrict__ xq, const u16* __restrict__ xkv,
    const u16* __restrict__ wq_t, const u16* __restrict__ wkv_t,
    const float* __restrict__ bq, const float* __restrict__ bk,
    const float* __restrict__ bv, const int* __restrict__ vmask,
    u16* __restrict__ Qh, u16* __restrict__ Kh, u16* __restrict__ VTh) {
    const int bid = blockIdx.x;
    const int swz = (bid & 7) * 160 + (bid >> 3);
    const bool isQ = swz < 256;
    int m0, n0;
    const u16 *A, *Bt;
    if (isQ) {
        m0 = (swz >> 3) * 128; n0 = (swz & 7) * 128;
        A = xq; Bt = wq_t;
    } else {
        int t2 = swz - 256;
        m0 = (t2 >> 4) * 128; n0 = (t2 & 15) * 128;
        A = xkv; Bt = wkv_t;
    }
    const bool isV = !isQ && n0 >= 1024;

    __shared__ __align__(16) u16 As[128 * 32];
    __shared__ __align__(16) u16 Bs[128 * 32];
    const int tid = threadIdx.x;
    const int lane = tid & 63, w = tid >> 6;
    const int wr = w >> 2, wc = w & 3;
    const int lr = lane & 15, lg = lane >> 4;
    const int ko = lg * 8;

    f32x4 acc[4][2];
#pragma unroll
    for (int i = 0; i < 4; i++)
#pragma unroll
        for (int j = 0; j < 2; j++)
#pragma unroll
            for (int r = 0; r < 4; r++) acc[i][j][r] = 0.f;

    const int srow = tid >> 2, spart = tid & 3;
    const u16* Ag = A + (size_t)(m0 + srow) * ND + spart * 8;
    const u16* Bg = Bt + (size_t)(n0 + srow) * ND + spart * 8;
    u16* lA = &As[w * 512];
    u16* lB = &Bs[w * 512];

    for (int kt = 0; kt < ND; kt += 32) {
        GL16(Ag + kt, lA);
        GL16(Bg + kt, lB);
        __syncthreads();

        s16x8 af[4], bf[2];
#pragma unroll
        for (int i = 0; i < 4; i++)
            af[i] = *(const s16x8*)&As[(wr * 64 + i * 16 + lr) * 32 + ko];
#pragma unroll
        for (int j = 0; j < 2; j++)
            bf[j] = *(const s16x8*)&Bs[(wc * 32 + j * 16 + lr) * 32 + ko];
        if (isV) {
#pragma unroll
            for (int mi = 0; mi < 4; mi++)
#pragma unroll
                for (int ni = 0; ni < 2; ni++)
                    acc[mi][ni] = __builtin_amdgcn_mfma_f32_16x16x32_bf16(
                        bf[ni], af[mi], acc[mi][ni], 0, 0, 0);
        } else {
#pragma unroll
            for (int mi = 0; mi < 4; mi++)
#pragma unroll
                for (int ni = 0; ni < 2; ni++)
                    acc[mi][ni] = __builtin_amdgcn_mfma_f32_16x16x32_bf16(
                        af[mi], bf[ni], acc[mi][ni], 0, 0, 0);
        }
        __syncthreads();
    }

#pragma unroll
    for (int mi = 0; mi < 4; mi++)
#pragma unroll
        for (int ni = 0; ni < 2; ni++)
#pragma unroll
            for (int r = 0; r < 4; r++) {
                if (isQ) {
                    int m = m0 + wr * 64 + mi * 16 + lg * 4 + r;
                    int n = n0 + wc * 32 + ni * 16 + lr;
                    int h = n >> 6, d = n & 63;
                    int b = m >> 11, lq = m & 2047;
                    Qh[((((size_t)b * NH + h) * NLQ + lq) << 6) + d] =
                        f2bf((acc[mi][ni][r] + bq[n]) * QSC);
                } else if (!isV) {
                    int m = m0 + wr * 64 + mi * 16 + lg * 4 + r;
                    int n = n0 + wc * 32 + ni * 16 + lr;
                    int h = n >> 6, d = n & 63;
                    int b = m >> 12, lkv = m & 4095;
                    Kh[((((size_t)b * NH + h) * NLKV + lkv) << 6) + d] =
                        f2bf(acc[mi][ni][r] + bk[n]);
                } else {
                    // transposed acc: row = n2 (d-dim), col = m (lkv, 16 consecutive)
                    int n2 = (n0 - 1024) + wc * 32 + ni * 16 + lg * 4 + r;
                    int m = m0 + wr * 64 + mi * 16 + lr;
                    int h = n2 >> 6, d = n2 & 63;
                    int b = m >> 12, lkv = m & 4095;
                    float val = vmask[(size_t)b * NLKV + lkv]
                                    ? acc[mi][ni][r] + bv[n2] : 0.f;
                    VTh[(((size_t)b * NH + h) * NHD + d) * NLKV + lkv] = f2bf(val);
                }
            }
}

// ---------- O-projection GEMM (f32 out) ----------
__global__ __launch_bounds__(512) void ogemm_kernel(
    const u16* __restrict__ A, const u16* __restrict__ Bt,
    const float* __restrict__ bias, float* __restrict__ Cout) {
    __shared__ __align__(16) u16 As[128 * 32];
    __shared__ __align__(16) u16 Bs[128 * 32];
    const int m0 = blockIdx.x * 128;
    const int n0 = blockIdx.y * 128;
    const int tid = threadIdx.x;
    const int lane = tid & 63, w = tid >> 6;
    const int wr = w >> 2, wc = w & 3;
    const int lr = lane & 15, lg = lane >> 4;
    const int ko = lg * 8;

    f32x4 acc[4][2];
#pragma unroll
    for (int i = 0; i < 4; i++)
#pragma unroll
        for (int j = 0; j < 2; j++)
#pragma unroll
            for (int r = 0; r < 4; r++) acc[i][j][r] = 0.f;

    const int srow = tid >> 2, spart = tid & 3;
    const u16* Ag = A + (size_t)(m0 + srow) * ND + spart * 8;
    const u16* Bg = Bt + (size_t)(n0 + srow) * ND + spart * 8;
    u16* lA = &As[w * 512];
    u16* lB = &Bs[w * 512];

    for (int kt = 0; kt < ND; kt += 32) {
        GL16(Ag + kt, lA);
        GL16(Bg + kt, lB);
        __syncthreads();

        s16x8 af[4], bf[2];
#pragma unroll
        for (int i = 0; i < 4; i++)
            af[i] = *(const s16x8*)&As[(wr * 64 + i * 16 + lr) * 32 + ko];
#pragma unroll
        for (int j = 0; j < 2; j++)
            bf[j] = *(const s16x8*)&Bs[(wc * 32 + j * 16 + lr) * 32 + ko];
#pragma unroll
        for (int mi = 0; mi < 4; mi++)
#pragma unroll
            for (int ni = 0; ni < 2; ni++)
                acc[mi][ni] = __builtin_amdgcn_mfma_f32_16x16x32_bf16(
                    af[mi], bf[ni], acc[mi][ni], 0, 0, 0);
        __syncthreads();
    }

#pragma unroll
    for (int mi = 0; mi < 4; mi++)
#pragma unroll
        for (int ni = 0; ni < 2; ni++)
#pragma unroll
            for (int r = 0; r < 4; r++) {
                int m = m0 + wr * 64 + mi * 16 + lg * 4 + r;
                int n = n0 + wc * 32 + ni * 16 + lr;
                Cout[(size_t)m * ND + n] = acc[mi][ni][r] + bias[n];
            }
}

// ---------- flash attention: R13 body + full-rank swizzle (c7 ^ c3) ----------
// grid (16, 32). l = bx + 16*by; bh = (l&7)*4 + ((l>>3)&3), qt = l>>5 (XCD
// bh-locality: 4 bh per XCD, KV L2-resident — R13-measured FETCH 135->20.5MB).
// Swizzle key now (row&7) ^ ((row>>3)&3): rows 8/16/24 apart land on distinct
// slots -> fragment reads spread over all 32 banks (kills the 4-way conflict;
// R13 measured 8.5M conflict cycles). key(row+32)==key(row) so one sx8 serves
// both staged rows; bijective per row.
__global__ __launch_bounds__(256) void attn_kernel(
    const u16* __restrict__ Qh, const u16* __restrict__ Kh,
    const u16* __restrict__ VTh, const u16* __restrict__ mbf,
    u16* __restrict__ attn) {
    const int l = blockIdx.x + 16 * blockIdx.y;
    const int qt = l >> 5;
    const int bh = (l & 7) * 4 + ((l >> 3) & 3);
    const int b = bh >> 4, h = bh & 15;
    const int tid = threadIdx.x;
    const int lane = tid & 63, w = tid >> 6;
    const int c = lane & 31, hi = lane >> 5;
    const int c7 = c & 7, c3 = (c >> 3) & 3;

    __shared__ __align__(16) u16 kt[2][4096];
    __shared__ __align__(16) u16 vt[2][4096];

    const int qw0 = qt * 128 + w * 32;
    const u16* Qb = Qh + (size_t)bh * NLQ * NHD;
    const u16* Kb = Kh + (size_t)bh * NLKV * NHD;
    const u16* VTb = VTh + (size_t)bh * NHD * NLKV;
    const u16* mbfb = mbf + (size_t)b * NLKV;

    // Q B-fragments: lane holds Q[qw0+c][kb*16 + hi*8 .. +7]
    s16x8 qa[4];
#pragma unroll
    for (int kb = 0; kb < 4; kb++)
        qa[kb] = *(const s16x8*)(Qb + (size_t)(qw0 + c) * NHD + kb * 16 + hi * 8);

    f32x16 o0, o1, lacc;
#pragma unroll
    for (int r = 0; r < 16; r++) { o0[r] = 0.f; o1[r] = 0.f; lacc[r] = 0.f; }

    // staging: row srow & srow+32, chunk sj; LDS slot j holds logical chunk
    // j ^ (row&7) ^ ((row>>3)&3)   (key(row+32) == key(row))
    const int srow = 8 * w + (lane >> 3);
    const int sj = lane & 7;
    const int sx8 = (sj ^ (srow & 7) ^ ((srow >> 3) & 3)) * 8;
    const u16* kS1 = Kb + (size_t)srow * NHD + sx8;
    const u16* kS2 = Kb + (size_t)(srow + 32) * NHD + sx8;
    const u16* vS1 = VTb + (size_t)srow * NLKV + sx8;
    const u16* vS2 = VTb + (size_t)(srow + 32) * NLKV + sx8;
    const int d1 = w * 512, d2 = 2048 + w * 512;

    // prologue: stage tile 0 into buffer 0
    GL16(kS1, &kt[0][d1]);
    GL16(kS2, &kt[0][d2]);
    GL16(vS1, &vt[0][d1]);
    GL16(vS2, &vt[0][d2]);

    const int NT = NLKV / 64;
    for (int t = 0; t < NT; t++) {
        const int cur = t & 1;
        __syncthreads();  // buf[cur] staged (vmcnt drained) + buf[cur^1] free
        if (t + 1 < NT) {
            size_t kvo = (size_t)(t + 1) * 64;
            GL16(kS1 + kvo * NHD, &kt[cur ^ 1][d1]);
            GL16(kS2 + kvo * NHD, &kt[cur ^ 1][d2]);
            GL16(vS1 + kvo, &vt[cur ^ 1][d1]);
            GL16(vS2 + kvo, &vt[cur ^ 1][d2]);
        }
        // mask A-fragments (broadcast rows)
        s16x8 mf[4];
#pragma unroll
        for (int pb = 0; pb < 4; pb++)
            mf[pb] = *(const s16x8*)(mbfb + t * 64 + pb * 16 + hi * 8);

        const u16* ktc = kt[cur];
        const u16* vtc = vt[cur];

        // QK^T swapped: s0 = S^T rows kv 0..31, s1 = rows 32..63; col q = c
        f32x16 s0, s1;
#pragma unroll
        for (int r = 0; r < 16; r++) { s0[r] = 0.f; s1[r] = 0.f; }
#pragma unroll
        for (int kb = 0; kb < 4; kb++) {
            int slot = ((kb * 2 + hi) ^ c7 ^ c3) << 3;
            s16x8 kf0 = *(const s16x8*)&ktc[c * 64 + slot];
            s16x8 kf1 = *(const s16x8*)&ktc[(32 + c) * 64 + slot];
            s0 = __builtin_amdgcn_mfma_f32_32x32x16_bf16(kf0, qa[kb], s0, 0, 0, 0);
            s1 = __builtin_amdgcn_mfma_f32_32x32x16_bf16(kf1, qa[kb], s1, 0, 0, 0);
        }

        // softmax: pure exp2 (Q pre-scaled; mask via V-zeroing + l-MFMA)
        float p0a[16], p1a[16];
#pragma unroll
        for (int r = 0; r < 16; r++) {
            p0a[r] = fast_exp2(s0[r]);
            p1a[r] = fast_exp2(s1[r]);
        }

        // pack to bf16 pairs + permlane swap -> PV B-fragments
        u32 pka[8], pkb2[8];
#pragma unroll
        for (int i = 0; i < 8; i++) {
            pka[i] = pkbf(p0a[2 * i], p0a[2 * i + 1]);
            pkb2[i] = pkbf(p1a[2 * i], p1a[2 * i + 1]);
        }
        pl32swap(pka[0], pka[2]); pl32swap(pka[1], pka[3]);
        pl32swap(pka[4], pka[6]); pl32swap(pka[5], pka[7]);
        pl32swap(pkb2[0], pkb2[2]); pl32swap(pkb2[1], pkb2[3]);
        pl32swap(pkb2[4], pkb2[6]); pl32swap(pkb2[5], pkb2[7]);

        union { u32 u[4]; s16x8 h; } fr[4];
#pragma unroll
        for (int i = 0; i < 4; i++) {
            fr[0].u[i] = pka[i];
            fr[1].u[i] = pka[4 + i];
            fr[2].u[i] = pkb2[i];
            fr[3].u[i] = pkb2[4 + i];
        }

        // PV: O^T[d][q=c] += V^T[d][kv] * P ; l via mask-MFMA on same P frags
#pragma unroll
        for (int pb = 0; pb < 4; pb++) {
            int slot = ((pb * 2 + hi) ^ c7 ^ c3) << 3;
            s16x8 vf0 = *(const s16x8*)&vtc[c * 64 + slot];
            s16x8 vf1 = *(const s16x8*)&vtc[(32 + c) * 64 + slot];
            o0 = __builtin_amdgcn_mfma_f32_32x32x16_bf16(vf0, fr[pb].h, o0, 0, 0, 0);
            o1 = __builtin_amdgcn_mfma_f32_32x32x16_bf16(vf1, fr[pb].h, o1, 0, 0, 0);
            lacc = __builtin_amdgcn_mfma_f32_32x32x16_bf16(mf[pb], fr[pb].h, lacc, 0, 0, 0);
        }
    }

    // lacc rows are all identical = l[q=c] over the full kv range
    float linv = 1.f / lacc[0];

    // epilogue: transpose O through LDS (reuse kt), coalesced global write.
    // (self-consistent c7-only swizzle pair; runs once per block)
    __syncthreads();
    u32* osh = (u32*)kt + w * 1024;  // per-wave [32 rows][32 dwords]
#pragma unroll
    for (int r = 0; r < 16; r += 2) {
        int d = (r & 3) + 8 * (r >> 2) + 4 * hi;
        u32 plo = pkbf(o0[r] * linv, o0[r + 1] * linv);
        u32 phi = pkbf(o1[r] * linv, o1[r + 1] * linv);
        int dc0 = d >> 1, dc1 = (d + 32) >> 1;
        osh[c * 32 + (((dc0 >> 2) ^ c7) << 2) + (dc0 & 3)] = plo;
        osh[c * 32 + (((dc1 >> 2) ^ c7) << 2) + (dc1 & 3)] = phi;
    }
    __syncthreads();
#pragma unroll
    for (int i = 0; i < 4; i++) {
        int row = 8 * i + (lane >> 3);
        int jj = lane & 7;
        u32 v0 = osh[row * 32 + ((jj ^ (row & 7)) << 2) + 0];
        u32 v1 = osh[row * 32 + ((jj ^ (row & 7)) << 2) + 1];
        u32 v2 = osh[row * 32 + ((jj ^ (row & 7)) << 2) + 2];
        u32 v3 = osh[row * 32 + ((jj ^ (row & 7)) << 2) + 3];
        u32* gp = (u32*)(attn + ((size_t)b * NLQ + qw0 + row) * ND + h * NHD + jj * 8);
        gp[0] = v0; gp[1] = v1; gp[2] = v2; gp[3] = v3;
    }
}

extern "C" void kernel_launch(void* const* d_in, const int* in_sizes, int n_in,
                              void* d_out, int out_size, void* d_ws, size_t ws_size,
                              hipStream_t stream) {
    const float* x_q = (const float*)d_in[0];
    const float* x_kv = (const float*)d_in[1];
    const int* mask = (const int*)d_in[2];
    const float* Wq = (const float*)d_in[3];
    const float* bq = (const float*)d_in[4];
    const float* Wk = (const float*)d_in[5];
    const float* bk = (const float*)d_in[6];
    const float* Wv = (const float*)d_in[7];
    const float* bv = (const float*)d_in[8];
    const float* Wo = (const float*)d_in[9];
    const float* bo = (const float*)d_in[10];
    float* out = (float*)d_out;

    size_t off = 0;
    auto carve = [&](size_t bytes) {
        void* p = (char*)d_ws + off;
        off += (bytes + 255) & ~(size_t)255;
        return p;
    };
    u16* xq_bf = (u16*)carve((size_t)NB * NLQ * ND * 2);
    u16* xkv_bf = (u16*)carve((size_t)NB * NLKV * ND * 2);
    u16* wq_t = (u16*)carve((size_t)ND * ND * 2);
    u16* wkv_t = (u16*)carve((size_t)2 * ND * ND * 2);
    u16* wo_t = (u16*)carve((size_t)ND * ND * 2);
    u16* Qh = (u16*)carve((size_t)NB * NH * NLQ * NHD * 2);
    u16* Kh = (u16*)carve((size_t)NB * NH * NLKV * NHD * 2);
    u16* VTh = (u16*)carve((size_t)NB * NH * NLKV * NHD * 2);
    u16* attn_bf = (u16*)carve((size_t)NB * NLQ * ND * 2);
    u16* mbfw = (u16*)carve((size_t)NB * NLKV * 2);

    cvt2_kernel<<<dim3(6144), 256, 0, stream>>>(x_q, x_kv, xq_bf, xkv_bf);
    mbf_kernel<<<dim3((NB * NLKV) / 256), 256, 0, stream>>>(mask, mbfw);
    tcvt_kernel<<<dim3(32, 32, 4), dim3(32, 8), 0, stream>>>(
        Wq, Wk, Wv, Wo, wq_t, wkv_t, wkv_t + (size_t)ND * ND, wo_t);
    qkv_kernel<<<dim3(1280), 512, 0, stream>>>(xq_bf, xkv_bf, wq_t, wkv_t,
                                               bq, bk, bv, mask, Qh, Kh, VTh);
    attn_kernel<<<dim3(NLQ / 128, NB * NH), 256, 0, stream>>>(Qh, Kh, VTh, mbfw, attn_bf);
    ogemm_kernel<<<dim3(32, 8), 512, 0, stream>>>(attn_bf, wo_t, bo, out);
}

// Round 15
// 229.709 us; speedup vs baseline: 1.0270x; 1.0270x over previous
//
#include <hip/hip_runtime.h>
#include <hip/hip_bf16.h>

typedef unsigned short u16;
typedef unsigned int u32;
typedef __attribute__((ext_vector_type(8))) unsigned short u16x8;
typedef __attribute__((ext_vector_type(8))) short s16x8;
typedef __attribute__((ext_vector_type(4))) float f32x4;
typedef __attribute__((ext_vector_type(16))) float f32x16;

#define NB 2
#define NLQ 2048
#define NLKV 4096
#define ND 1024
#define NH 16
#define NHD 64
#define SCALE 0.125f
#define QSC (SCALE * 1.44269504f)  // fold scale+log2e into Q

// async global->LDS, 16B per lane; dest = uniform base + lane*16
#define GL16(g, l)                                                            \
    __builtin_amdgcn_global_load_lds(                                         \
        (const __attribute__((address_space(1))) void*)(g),                   \
        (__attribute__((address_space(3))) void*)(l), 16, 0, 0)

__device__ __forceinline__ u16 f2bf(float f) {
    __hip_bfloat16 h = __float2bfloat16(f);
    return *(u16*)&h;
}

__device__ __forceinline__ float b2f(u32 lo16) {
    union { u32 u; float f; } v;
    v.u = lo16 << 16;
    return v.f;
}

__device__ __forceinline__ float fast_exp2(float x) {
    float r;
    asm("v_exp_f32 %0, %1" : "=v"(r) : "v"(x));
    return r;
}

__device__ __forceinline__ u32 pkbf(float lo, float hi_) {
    u32 r;
    asm("v_cvt_pk_bf16_f32 %0, %1, %2" : "=v"(r) : "v"(lo), "v"(hi_));
    return r;
}

// vdst.hi32lanes <-> vsrc.lo32lanes
__device__ __forceinline__ void pl32swap(u32& a, u32& b) {
    asm("v_permlane32_swap_b32 %0, %1" : "+v"(a), "+v"(b));
}

// ---------- fused f32 -> bf16 for x_q and x_kv (one launch) ----------
__global__ __launch_bounds__(256) void cvt2_kernel(const float* __restrict__ xq,
                                                   const float* __restrict__ xkv,
                                                   u16* __restrict__ oq,
                                                   u16* __restrict__ okv) {
    int bid = blockIdx.x;
    const float* in;
    u16* out;
    int i0;
    if (bid < 2048) { in = xq; out = oq; i0 = bid; }
    else { in = xkv; out = okv; i0 = bid - 2048; }
    int i = i0 * 256 + threadIdx.x;
    const float4* p = (const float4*)in;
    float4 a = p[2 * i], b = p[2 * i + 1];
    u16x8 o;
    o[0] = f2bf(a.x); o[1] = f2bf(a.y); o[2] = f2bf(a.z); o[3] = f2bf(a.w);
    o[4] = f2bf(b.x); o[5] = f2bf(b.y); o[6] = f2bf(b.z); o[7] = f2bf(b.w);
    ((u16x8*)out)[i] = o;
}

// ---------- mask int32 -> bf16 {0,1} ----------
__global__ __launch_bounds__(256) void mbf_kernel(const int* __restrict__ mask,
                                                  u16* __restrict__ mbf) {
    int g = blockIdx.x * 256 + threadIdx.x;
    mbf[g] = mask[g] ? 0x3F80 : 0;  // bf16 1.0
}

// ---------- W[k][n] f32 -> Wt[n][k] bf16, 4 weights ----------
__global__ __launch_bounds__(256) void tcvt_kernel(
    const float* __restrict__ w0, const float* __restrict__ w1,
    const float* __restrict__ w2, const float* __restrict__ w3,
    u16* __restrict__ o0, u16* __restrict__ o1,
    u16* __restrict__ o2, u16* __restrict__ o3) {
    const float* w = blockIdx.z == 0 ? w0 : blockIdx.z == 1 ? w1 : blockIdx.z == 2 ? w2 : w3;
    u16* o = blockIdx.z == 0 ? o0 : blockIdx.z == 1 ? o1 : blockIdx.z == 2 ? o2 : o3;
    __shared__ float t[32][33];
    int n0 = blockIdx.x * 32, k0 = blockIdx.y * 32;
    int tx = threadIdx.x, ty = threadIdx.y;
#pragma unroll
    for (int i = 0; i < 4; i++) t[ty + 8 * i][tx] = w[(k0 + ty + 8 * i) * ND + n0 + tx];
    __syncthreads();
#pragma unroll
    for (int i = 0; i < 4; i++) o[(n0 + ty + 8 * i) * ND + k0 + tx] = f2bf(t[tx][ty + 8 * i]);
}

// ---------- unified QKV projection GEMM: 1280 blocks (256 Q + 1024 KV) ----------
// XCD-bijective swizzle (1280 = 8*160). tile 128x128, BK=32, 8 waves 2x4, GL16.
// V-half blocks swap MFMA operands -> D^T in acc -> coalesced V^T store.
__global__ __launch_bounds__(512) void qkv_kernel(
    const u16* __restrict__ xq, const u16* __restrict__ xkv,
    const u16* __restrict__ wq_t, const u16* __restrict__ wkv_t,
    const float* __restrict__ bq, const float* __restrict__ bk,
    const float* __restrict__ bv, const int* __restrict__ vmask,
    u16* __restrict__ Qh, u16* __restrict__ Kh, u16* __restrict__ VTh) {
    const int bid = blockIdx.x;
    const int swz = (bid & 7) * 160 + (bid >> 3);
    const bool isQ = swz < 256;
    int m0, n0;
    const u16 *A, *Bt;
    if (isQ) {
        m0 = (swz >> 3) * 128; n0 = (swz & 7) * 128;
        A = xq; Bt = wq_t;
    } else {
        int t2 = swz - 256;
        m0 = (t2 >> 4) * 128; n0 = (t2 & 15) * 128;
        A = xkv; Bt = wkv_t;
    }
    const bool isV = !isQ && n0 >= 1024;

    __shared__ __align__(16) u16 As[128 * 32];
    __shared__ __align__(16) u16 Bs[128 * 32];
    const int tid = threadIdx.x;
    const int lane = tid & 63, w = tid >> 6;
    const int wr = w >> 2, wc = w & 3;
    const int lr = lane & 15, lg = lane >> 4;
    const int ko = lg * 8;

    f32x4 acc[4][2];
#pragma unroll
    for (int i = 0; i < 4; i++)
#pragma unroll
        for (int j = 0; j < 2; j++)
#pragma unroll
            for (int r = 0; r < 4; r++) acc[i][j][r] = 0.f;

    const int srow = tid >> 2, spart = tid & 3;
    const u16* Ag = A + (size_t)(m0 + srow) * ND + spart * 8;
    const u16* Bg = Bt + (size_t)(n0 + srow) * ND + spart * 8;
    u16* lA = &As[w * 512];
    u16* lB = &Bs[w * 512];

    for (int kt = 0; kt < ND; kt += 32) {
        GL16(Ag + kt, lA);
        GL16(Bg + kt, lB);
        __syncthreads();

        s16x8 af[4], bf[2];
#pragma unroll
        for (int i = 0; i < 4; i++)
            af[i] = *(const s16x8*)&As[(wr * 64 + i * 16 + lr) * 32 + ko];
#pragma unroll
        for (int j = 0; j < 2; j++)
            bf[j] = *(const s16x8*)&Bs[(wc * 32 + j * 16 + lr) * 32 + ko];
        if (isV) {
#pragma unroll
            for (int mi = 0; mi < 4; mi++)
#pragma unroll
                for (int ni = 0; ni < 2; ni++)
                    acc[mi][ni] = __builtin_amdgcn_mfma_f32_16x16x32_bf16(
                        bf[ni], af[mi], acc[mi][ni], 0, 0, 0);
        } else {
#pragma unroll
            for (int mi = 0; mi < 4; mi++)
#pragma unroll
                for (int ni = 0; ni < 2; ni++)
                    acc[mi][ni] = __builtin_amdgcn_mfma_f32_16x16x32_bf16(
                        af[mi], bf[ni], acc[mi][ni], 0, 0, 0);
        }
        __syncthreads();
    }

#pragma unroll
    for (int mi = 0; mi < 4; mi++)
#pragma unroll
        for (int ni = 0; ni < 2; ni++)
#pragma unroll
            for (int r = 0; r < 4; r++) {
                if (isQ) {
                    int m = m0 + wr * 64 + mi * 16 + lg * 4 + r;
                    int n = n0 + wc * 32 + ni * 16 + lr;
                    int h = n >> 6, d = n & 63;
                    int b = m >> 11, lq = m & 2047;
                    Qh[((((size_t)b * NH + h) * NLQ + lq) << 6) + d] =
                        f2bf((acc[mi][ni][r] + bq[n]) * QSC);
                } else if (!isV) {
                    int m = m0 + wr * 64 + mi * 16 + lg * 4 + r;
                    int n = n0 + wc * 32 + ni * 16 + lr;
                    int h = n >> 6, d = n & 63;
                    int b = m >> 12, lkv = m & 4095;
                    Kh[((((size_t)b * NH + h) * NLKV + lkv) << 6) + d] =
                        f2bf(acc[mi][ni][r] + bk[n]);
                } else {
                    // transposed acc: row = n2 (d-dim), col = m (lkv, 16 consecutive)
                    int n2 = (n0 - 1024) + wc * 32 + ni * 16 + lg * 4 + r;
                    int m = m0 + wr * 64 + mi * 16 + lr;
                    int h = n2 >> 6, d = n2 & 63;
                    int b = m >> 12, lkv = m & 4095;
                    float val = vmask[(size_t)b * NLKV + lkv]
                                    ? acc[mi][ni][r] + bv[n2] : 0.f;
                    VTh[(((size_t)b * NH + h) * NHD + d) * NLKV + lkv] = f2bf(val);
                }
            }
}

// ---------- O-projection GEMM (f32 out), 64x128 tile -> 512 blocks (2/CU) ----------
// 256 thr = 4 waves 2x2; wave tile 32x64 (acc[2][4]). GL16 staging, BK=32.
__global__ __launch_bounds__(256) void ogemm_kernel(
    const u16* __restrict__ A, const u16* __restrict__ Bt,
    const float* __restrict__ bias, float* __restrict__ Cout) {
    __shared__ __align__(16) u16 As[64 * 32];
    __shared__ __align__(16) u16 Bs[128 * 32];
    const int m0 = blockIdx.x * 64;
    const int n0 = blockIdx.y * 128;
    const int tid = threadIdx.x;
    const int lane = tid & 63, w = tid >> 6;
    const int wr = w >> 1, wc = w & 1;  // 2x2 wave grid
    const int lr = lane & 15, lg = lane >> 4;
    const int ko = lg * 8;

    f32x4 acc[2][4];
#pragma unroll
    for (int i = 0; i < 2; i++)
#pragma unroll
        for (int j = 0; j < 4; j++)
#pragma unroll
            for (int r = 0; r < 4; r++) acc[i][j][r] = 0.f;

    const int srow = tid >> 2, spart = tid & 3;
    const u16* Ag = A + (size_t)(m0 + srow) * ND + spart * 8;
    const u16* Bg = Bt + (size_t)(n0 + srow) * ND + spart * 8;
    const u16* Bg2 = Bt + (size_t)(n0 + 64 + srow) * ND + spart * 8;
    u16* lA = &As[w * 512];
    u16* lB = &Bs[w * 512];
    u16* lB2 = &Bs[2048 + w * 512];

    for (int kt = 0; kt < ND; kt += 32) {
        GL16(Ag + kt, lA);
        GL16(Bg + kt, lB);
        GL16(Bg2 + kt, lB2);
        __syncthreads();

        s16x8 af[2], bf[4];
#pragma unroll
        for (int i = 0; i < 2; i++)
            af[i] = *(const s16x8*)&As[(wr * 32 + i * 16 + lr) * 32 + ko];
#pragma unroll
        for (int j = 0; j < 4; j++)
            bf[j] = *(const s16x8*)&Bs[(wc * 64 + j * 16 + lr) * 32 + ko];
#pragma unroll
        for (int mi = 0; mi < 2; mi++)
#pragma unroll
            for (int ni = 0; ni < 4; ni++)
                acc[mi][ni] = __builtin_amdgcn_mfma_f32_16x16x32_bf16(
                    af[mi], bf[ni], acc[mi][ni], 0, 0, 0);
        __syncthreads();
    }

#pragma unroll
    for (int mi = 0; mi < 2; mi++)
#pragma unroll
        for (int ni = 0; ni < 4; ni++)
#pragma unroll
            for (int r = 0; r < 4; r++) {
                int m = m0 + wr * 32 + mi * 16 + lg * 4 + r;
                int n = n0 + wc * 64 + ni * 16 + lr;
                Cout[(size_t)m * ND + n] = acc[mi][ni][r] + bias[n];
            }
}

// ---------- flash attention: R14 body + z=2 KV-split (grid-level) ----------
// grid (16, 32, 2). l = bx + 16*by; bh = (l&7)*4 + ((l>>3)&3), qt = l>>5 (XCD
// bh-locality, R13: FETCH 135->20.5MB). z-half zh processes kv [zh*2048,+2048)
// (NT=32) with the proven loop + full-rank swizzle (R14: conflicts 8.5M->197K),
// then dumps bf16-packed O-partials + f32 l (coalesced); amerge combines.
// 1024 blocks -> 4 blocks/CU -> 4 waves/SIMD (R10 retest, now L2-resident).
__global__ __launch_bounds__(256) void attn_kernel(
    const u16* __restrict__ Qh, const u16* __restrict__ Kh,
    const u16* __restrict__ VTh, const u16* __restrict__ mbf,
    u32* __restrict__ pP, float* __restrict__ pL) {
    const int l = blockIdx.x + 16 * blockIdx.y;
    const int qt = l >> 5;
    const int bh = (l & 7) * 4 + ((l >> 3) & 3);
    const int zh = blockIdx.z;
    const int b = bh >> 4;
    const int tid = threadIdx.x;
    const int lane = tid & 63, w = tid >> 6;
    const int c = lane & 31, hi = lane >> 5;
    const int c7 = c & 7, c3 = (c >> 3) & 3;

    __shared__ __align__(16) u16 kt[2][4096];
    __shared__ __align__(16) u16 vt[2][4096];

    const int qw0 = qt * 128 + w * 32;
    const u16* Qb = Qh + (size_t)bh * NLQ * NHD;
    const u16* Kb = Kh + ((size_t)bh * NLKV + zh * 2048) * NHD;
    const u16* VTb = VTh + (size_t)bh * NHD * NLKV;
    const u16* mbfb = mbf + (size_t)b * NLKV + zh * 2048;

    // Q B-fragments: lane holds Q[qw0+c][kb*16 + hi*8 .. +7]
    s16x8 qa[4];
#pragma unroll
    for (int kb = 0; kb < 4; kb++)
        qa[kb] = *(const s16x8*)(Qb + (size_t)(qw0 + c) * NHD + kb * 16 + hi * 8);

    f32x16 o0, o1, lacc;
#pragma unroll
    for (int r = 0; r < 16; r++) { o0[r] = 0.f; o1[r] = 0.f; lacc[r] = 0.f; }

    // staging: row srow & srow+32, chunk sj; slot j holds logical chunk
    // j ^ (row&7) ^ ((row>>3)&3)   (key(row+32) == key(row))
    const int srow = 8 * w + (lane >> 3);
    const int sj = lane & 7;
    const int sx8 = (sj ^ (srow & 7) ^ ((srow >> 3) & 3)) * 8;
    const u16* kS1 = Kb + (size_t)srow * NHD + sx8;
    const u16* kS2 = Kb + (size_t)(srow + 32) * NHD + sx8;
    const u16* vS1 = VTb + (size_t)srow * NLKV + zh * 2048 + sx8;
    const u16* vS2 = VTb + (size_t)(srow + 32) * NLKV + zh * 2048 + sx8;
    const int d1 = w * 512, d2 = 2048 + w * 512;

    // prologue: stage tile 0 into buffer 0
    GL16(kS1, &kt[0][d1]);
    GL16(kS2, &kt[0][d2]);
    GL16(vS1, &vt[0][d1]);
    GL16(vS2, &vt[0][d2]);

    const int NT = 2048 / 64;
    for (int t = 0; t < NT; t++) {
        const int cur = t & 1;
        __syncthreads();  // buf[cur] staged (vmcnt drained) + buf[cur^1] free
        if (t + 1 < NT) {
            size_t kvo = (size_t)(t + 1) * 64;
            GL16(kS1 + kvo * NHD, &kt[cur ^ 1][d1]);
            GL16(kS2 + kvo * NHD, &kt[cur ^ 1][d2]);
            GL16(vS1 + kvo, &vt[cur ^ 1][d1]);
            GL16(vS2 + kvo, &vt[cur ^ 1][d2]);
        }
        // mask A-fragments (broadcast rows)
        s16x8 mf[4];
#pragma unroll
        for (int pb = 0; pb < 4; pb++)
            mf[pb] = *(const s16x8*)(mbfb + t * 64 + pb * 16 + hi * 8);

        const u16* ktc = kt[cur];
        const u16* vtc = vt[cur];

        // QK^T swapped: s0 = S^T rows kv 0..31, s1 = rows 32..63; col q = c
        f32x16 s0, s1;
#pragma unroll
        for (int r = 0; r < 16; r++) { s0[r] = 0.f; s1[r] = 0.f; }
#pragma unroll
        for (int kb = 0; kb < 4; kb++) {
            int slot = ((kb * 2 + hi) ^ c7 ^ c3) << 3;
            s16x8 kf0 = *(const s16x8*)&ktc[c * 64 + slot];
            s16x8 kf1 = *(const s16x8*)&ktc[(32 + c) * 64 + slot];
            s0 = __builtin_amdgcn_mfma_f32_32x32x16_bf16(kf0, qa[kb], s0, 0, 0, 0);
            s1 = __builtin_amdgcn_mfma_f32_32x32x16_bf16(kf1, qa[kb], s1, 0, 0, 0);
        }

        // softmax: pure exp2 (Q pre-scaled; mask via V-zeroing + l-MFMA)
        float p0a[16], p1a[16];
#pragma unroll
        for (int r = 0; r < 16; r++) {
            p0a[r] = fast_exp2(s0[r]);
            p1a[r] = fast_exp2(s1[r]);
        }

        // pack to bf16 pairs + permlane swap -> PV B-fragments
        u32 pka[8], pkb2[8];
#pragma unroll
        for (int i = 0; i < 8; i++) {
            pka[i] = pkbf(p0a[2 * i], p0a[2 * i + 1]);
            pkb2[i] = pkbf(p1a[2 * i], p1a[2 * i + 1]);
        }
        pl32swap(pka[0], pka[2]); pl32swap(pka[1], pka[3]);
        pl32swap(pka[4], pka[6]); pl32swap(pka[5], pka[7]);
        pl32swap(pkb2[0], pkb2[2]); pl32swap(pkb2[1], pkb2[3]);
        pl32swap(pkb2[4], pkb2[6]); pl32swap(pkb2[5], pkb2[7]);

        union { u32 u[4]; s16x8 h; } fr[4];
#pragma unroll
        for (int i = 0; i < 4; i++) {
            fr[0].u[i] = pka[i];
            fr[1].u[i] = pka[4 + i];
            fr[2].u[i] = pkb2[i];
            fr[3].u[i] = pkb2[4 + i];
        }

        // PV: O^T[d][q=c] += V^T[d][kv] * P ; l via mask-MFMA on same P frags
#pragma unroll
        for (int pb = 0; pb < 4; pb++) {
            int slot = ((pb * 2 + hi) ^ c7 ^ c3) << 3;
            s16x8 vf0 = *(const s16x8*)&vtc[c * 64 + slot];
            s16x8 vf1 = *(const s16x8*)&vtc[(32 + c) * 64 + slot];
            o0 = __builtin_amdgcn_mfma_f32_32x32x16_bf16(vf0, fr[pb].h, o0, 0, 0, 0);
            o1 = __builtin_amdgcn_mfma_f32_32x32x16_bf16(vf1, fr[pb].h, o1, 0, 0, 0);
            lacc = __builtin_amdgcn_mfma_f32_32x32x16_bf16(mf[pb], fr[pb].h, lacc, 0, 0, 0);
        }
    }

    // raw partial dump: 16 u32 (bf16 pairs) per lane, fully coalesced
    size_t pbase = ((((size_t)zh * (NB * NH) + bh) * 16 + qt) * 4 + w) * 1024;
#pragma unroll
    for (int i = 0; i < 8; i++) {
        pP[pbase + i * 64 + lane] = pkbf(o0[2 * i], o0[2 * i + 1]);
        pP[pbase + (8 + i) * 64 + lane] = pkbf(o1[2 * i], o1[2 * i + 1]);
    }
    pL[(((size_t)zh * (NB * NH) + bh) * 16 + qt) * 256 + w * 64 + lane] = lacc[0];
}

// ---------- merge + normalize + transpose epilogue (R10-verified) ----------
__global__ __launch_bounds__(256) void amerge_kernel(
    const u32* __restrict__ pP, const float* __restrict__ pL,
    u16* __restrict__ attn) {
    const int qt = blockIdx.x;
    const int bh = blockIdx.y;
    const int b = bh >> 4, h = bh & 15;
    const int tid = threadIdx.x;
    const int lane = tid & 63, w = tid >> 6;
    const int c = lane & 31, hi = lane >> 5;
    const int c7 = c & 7;

    __shared__ u32 oshb[4][1024];

    size_t p0 = ((((size_t)0 * (NB * NH) + bh) * 16 + qt) * 4 + w) * 1024;
    size_t p1 = ((((size_t)1 * (NB * NH) + bh) * 16 + qt) * 4 + w) * 1024;

    float o0[16], o1[16];
#pragma unroll
    for (int i = 0; i < 8; i++) {
        u32 a0 = pP[p0 + i * 64 + lane], a1 = pP[p1 + i * 64 + lane];
        o0[2 * i] = b2f(a0 & 0xffff) + b2f(a1 & 0xffff);
        o0[2 * i + 1] = b2f(a0 >> 16) + b2f(a1 >> 16);
        u32 e0 = pP[p0 + (8 + i) * 64 + lane], e1 = pP[p1 + (8 + i) * 64 + lane];
        o1[2 * i] = b2f(e0 & 0xffff) + b2f(e1 & 0xffff);
        o1[2 * i + 1] = b2f(e0 >> 16) + b2f(e1 >> 16);
    }
    float lsum = pL[(((size_t)0 * (NB * NH) + bh) * 16 + qt) * 256 + w * 64 + lane] +
                 pL[(((size_t)1 * (NB * NH) + bh) * 16 + qt) * 256 + w * 64 + lane];
    float linv = 1.f / lsum;

    u32* osh = oshb[w];
#pragma unroll
    for (int r = 0; r < 16; r += 2) {
        int d = (r & 3) + 8 * (r >> 2) + 4 * hi;
        u32 plo = pkbf(o0[r] * linv, o0[r + 1] * linv);
        u32 phi = pkbf(o1[r] * linv, o1[r + 1] * linv);
        int dc0 = d >> 1, dc1 = (d + 32) >> 1;
        osh[c * 32 + (((dc0 >> 2) ^ c7) << 2) + (dc0 & 3)] = plo;
        osh[c * 32 + (((dc1 >> 2) ^ c7) << 2) + (dc1 & 3)] = phi;
    }
#pragma unroll
    for (int i = 0; i < 4; i++) {
        int row = 8 * i + (lane >> 3);
        int jj = lane & 7;
        u32 v0 = osh[row * 32 + ((jj ^ (row & 7)) << 2) + 0];
        u32 v1 = osh[row * 32 + ((jj ^ (row & 7)) << 2) + 1];
        u32 v2 = osh[row * 32 + ((jj ^ (row & 7)) << 2) + 2];
        u32 v3 = osh[row * 32 + ((jj ^ (row & 7)) << 2) + 3];
        u32* gp = (u32*)(attn + ((size_t)b * NLQ + qt * 128 + w * 32 + row) * ND +
                         h * NHD + jj * 8);
        gp[0] = v0; gp[1] = v1; gp[2] = v2; gp[3] = v3;
    }
}

extern "C" void kernel_launch(void* const* d_in, const int* in_sizes, int n_in,
                              void* d_out, int out_size, void* d_ws, size_t ws_size,
                              hipStream_t stream) {
    const float* x_q = (const float*)d_in[0];
    const float* x_kv = (const float*)d_in[1];
    const int* mask = (const int*)d_in[2];
    const float* Wq = (const float*)d_in[3];
    const float* bq = (const float*)d_in[4];
    const float* Wk = (const float*)d_in[5];
    const float* bk = (const float*)d_in[6];
    const float* Wv = (const float*)d_in[7];
    const float* bv = (const float*)d_in[8];
    const float* Wo = (const float*)d_in[9];
    const float* bo = (const float*)d_in[10];
    float* out = (float*)d_out;

    size_t off = 0;
    auto carve = [&](size_t bytes) {
        void* p = (char*)d_ws + off;
        off += (bytes + 255) & ~(size_t)255;
        return p;
    };
    u16* xq_bf = (u16*)carve((size_t)NB * NLQ * ND * 2);    // 8MB  (dead after qkv)
    u16* xkv_bf = (u16*)carve((size_t)NB * NLKV * ND * 2);  // 16MB (dead after qkv)
    u16* wq_t = (u16*)carve((size_t)ND * ND * 2);           // 2MB  (dead after qkv)
    u16* wkv_t = (u16*)carve((size_t)2 * ND * ND * 2);
    u16* wo_t = (u16*)carve((size_t)ND * ND * 2);
    u16* Qh = (u16*)carve((size_t)NB * NH * NLQ * NHD * 2);
    u16* Kh = (u16*)carve((size_t)NB * NH * NLKV * NHD * 2);
    u16* VTh = (u16*)carve((size_t)NB * NH * NLKV * NHD * 2);
    u16* attn_bf = (u16*)carve((size_t)NB * NLQ * ND * 2);
    u16* mbfw = (u16*)carve((size_t)NB * NLKV * 2);

    // attn partials alias dead regions: pP (16.8MB) over xq_bf+xkv_bf, pL (1MB) over wq_t
    u32* pP = (u32*)xq_bf;
    float* pL = (float*)wq_t;

    cvt2_kernel<<<dim3(6144), 256, 0, stream>>>(x_q, x_kv, xq_bf, xkv_bf);
    mbf_kernel<<<dim3((NB * NLKV) / 256), 256, 0, stream>>>(mask, mbfw);
    tcvt_kernel<<<dim3(32, 32, 4), dim3(32, 8), 0, stream>>>(
        Wq, Wk, Wv, Wo, wq_t, wkv_t, wkv_t + (size_t)ND * ND, wo_t);
    qkv_kernel<<<dim3(1280), 512, 0, stream>>>(xq_bf, xkv_bf, wq_t, wkv_t,
                                               bq, bk, bv, mask, Qh, Kh, VTh);
    attn_kernel<<<dim3(16, 32, 2), 256, 0, stream>>>(Qh, Kh, VTh, mbfw, pP, pL);
    amerge_kernel<<<dim3(16, 32), 256, 0, stream>>>(pP, pL, attn_bf);
    ogemm_kernel<<<dim3(64, 8), 256, 0, stream>>>(attn_bf, wo_t, bo, out);
}

// Round 16
// 217.044 us; speedup vs baseline: 1.0869x; 1.0584x over previous
//
#include <hip/hip_runtime.h>
#include <hip/hip_bf16.h>

typedef unsigned short u16;
typedef unsigned int u32;
typedef __attribute__((ext_vector_type(8))) unsigned short u16x8;
typedef __attribute__((ext_vector_type(8))) short s16x8;
typedef __attribute__((ext_vector_type(4))) float f32x4;
typedef __attribute__((ext_vector_type(16))) float f32x16;

#define NB 2
#define NLQ 2048
#define NLKV 4096
#define ND 1024
#define NH 16
#define NHD 64
#define SCALE 0.125f
#define QSC (SCALE * 1.44269504f)  // fold scale+log2e into Q

// async global->LDS, 16B per lane; dest = uniform base + lane*16
#define GL16(g, l)                                                            \
    __builtin_amdgcn_global_load_lds(                                         \
        (const __attribute__((address_space(1))) void*)(g),                   \
        (__attribute__((address_space(3))) void*)(l), 16, 0, 0)

__device__ __forceinline__ u16 f2bf(float f) {
    __hip_bfloat16 h = __float2bfloat16(f);
    return *(u16*)&h;
}

__device__ __forceinline__ float fast_exp2(float x) {
    float r;
    asm("v_exp_f32 %0, %1" : "=v"(r) : "v"(x));
    return r;
}

__device__ __forceinline__ u32 pkbf(float lo, float hi_) {
    u32 r;
    asm("v_cvt_pk_bf16_f32 %0, %1, %2" : "=v"(r) : "v"(lo), "v"(hi_));
    return r;
}

// vdst.hi32lanes <-> vsrc.lo32lanes
__device__ __forceinline__ void pl32swap(u32& a, u32& b) {
    asm("v_permlane32_swap_b32 %0, %1" : "+v"(a), "+v"(b));
}

// ---------- fused f32->bf16 (x_q, x_kv) + mask->bf16 in one launch ----------
__global__ __launch_bounds__(256) void cvt2_kernel(const float* __restrict__ xq,
                                                   const float* __restrict__ xkv,
                                                   const int* __restrict__ mask,
                                                   u16* __restrict__ oq,
                                                   u16* __restrict__ okv,
                                                   u16* __restrict__ mbf) {
    int bid = blockIdx.x;
    if (bid >= 6144) {  // mask blocks: 32 blocks x 256 = 8192 ints
        int g = (bid - 6144) * 256 + threadIdx.x;
        mbf[g] = mask[g] ? 0x3F80 : 0;  // bf16 1.0
        return;
    }
    const float* in;
    u16* out;
    int i0;
    if (bid < 2048) { in = xq; out = oq; i0 = bid; }
    else { in = xkv; out = okv; i0 = bid - 2048; }
    int i = i0 * 256 + threadIdx.x;
    const float4* p = (const float4*)in;
    float4 a = p[2 * i], b = p[2 * i + 1];
    u16x8 o;
    o[0] = f2bf(a.x); o[1] = f2bf(a.y); o[2] = f2bf(a.z); o[3] = f2bf(a.w);
    o[4] = f2bf(b.x); o[5] = f2bf(b.y); o[6] = f2bf(b.z); o[7] = f2bf(b.w);
    ((u16x8*)out)[i] = o;
}

// ---------- W[k][n] f32 -> Wt[n][k] bf16, 4 weights ----------
__global__ __launch_bounds__(256) void tcvt_kernel(
    const float* __restrict__ w0, const float* __restrict__ w1,
    const float* __restrict__ w2, const float* __restrict__ w3,
    u16* __restrict__ o0, u16* __restrict__ o1,
    u16* __restrict__ o2, u16* __restrict__ o3) {
    const float* w = blockIdx.z == 0 ? w0 : blockIdx.z == 1 ? w1 : blockIdx.z == 2 ? w2 : w3;
    u16* o = blockIdx.z == 0 ? o0 : blockIdx.z == 1 ? o1 : blockIdx.z == 2 ? o2 : o3;
    __shared__ float t[32][33];
    int n0 = blockIdx.x * 32, k0 = blockIdx.y * 32;
    int tx = threadIdx.x, ty = threadIdx.y;
#pragma unroll
    for (int i = 0; i < 4; i++) t[ty + 8 * i][tx] = w[(k0 + ty + 8 * i) * ND + n0 + tx];
    __syncthreads();
#pragma unroll
    for (int i = 0; i < 4; i++) o[(n0 + ty + 8 * i) * ND + k0 + tx] = f2bf(t[tx][ty + 8 * i]);
}

// ---------- unified QKV projection GEMM: 1280 blocks (256 Q + 1024 KV) ----------
// XCD-bijective swizzle (1280 = 8*160). tile 128x128, BK=32, 8 waves 2x4, GL16.
// V-half blocks swap MFMA operands -> D^T in acc -> coalesced V^T store.
__global__ __launch_bounds__(512) void qkv_kernel(
    const u16* __restrict__ xq, const u16* __restrict__ xkv,
    const u16* __restrict__ wq_t, const u16* __restrict__ wkv_t,
    const float* __restrict__ bq, const float* __restrict__ bk,
    const float* __restrict__ bv, const int* __restrict__ vmask,
    u16* __restrict__ Qh, u16* __restrict__ Kh, u16* __restrict__ VTh) {
    const int bid = blockIdx.x;
    const int swz = (bid & 7) * 160 + (bid >> 3);
    const bool isQ = swz < 256;
    int m0, n0;
    const u16 *A, *Bt;
    if (isQ) {
        m0 = (swz >> 3) * 128; n0 = (swz & 7) * 128;
        A = xq; Bt = wq_t;
    } else {
        int t2 = swz - 256;
        m0 = (t2 >> 4) * 128; n0 = (t2 & 15) * 128;
        A = xkv; Bt = wkv_t;
    }
    const bool isV = !isQ && n0 >= 1024;

    __shared__ __align__(16) u16 As[128 * 32];
    __shared__ __align__(16) u16 Bs[128 * 32];
    const int tid = threadIdx.x;
    const int lane = tid & 63, w = tid >> 6;
    const int wr = w >> 2, wc = w & 3;
    const int lr = lane & 15, lg = lane >> 4;
    const int ko = lg * 8;

    f32x4 acc[4][2];
#pragma unroll
    for (int i = 0; i < 4; i++)
#pragma unroll
        for (int j = 0; j < 2; j++)
#pragma unroll
            for (int r = 0; r < 4; r++) acc[i][j][r] = 0.f;

    const int srow = tid >> 2, spart = tid & 3;
    const u16* Ag = A + (size_t)(m0 + srow) * ND + spart * 8;
    const u16* Bg = Bt + (size_t)(n0 + srow) * ND + spart * 8;
    u16* lA = &As[w * 512];
    u16* lB = &Bs[w * 512];

    for (int kt = 0; kt < ND; kt += 32) {
        GL16(Ag + kt, lA);
        GL16(Bg + kt, lB);
        __syncthreads();

        s16x8 af[4], bf[2];
#pragma unroll
        for (int i = 0; i < 4; i++)
            af[i] = *(const s16x8*)&As[(wr * 64 + i * 16 + lr) * 32 + ko];
#pragma unroll
        for (int j = 0; j < 2; j++)
            bf[j] = *(const s16x8*)&Bs[(wc * 32 + j * 16 + lr) * 32 + ko];
        if (isV) {
#pragma unroll
            for (int mi = 0; mi < 4; mi++)
#pragma unroll
                for (int ni = 0; ni < 2; ni++)
                    acc[mi][ni] = __builtin_amdgcn_mfma_f32_16x16x32_bf16(
                        bf[ni], af[mi], acc[mi][ni], 0, 0, 0);
        } else {
#pragma unroll
            for (int mi = 0; mi < 4; mi++)
#pragma unroll
                for (int ni = 0; ni < 2; ni++)
                    acc[mi][ni] = __builtin_amdgcn_mfma_f32_16x16x32_bf16(
                        af[mi], bf[ni], acc[mi][ni], 0, 0, 0);
        }
        __syncthreads();
    }

#pragma unroll
    for (int mi = 0; mi < 4; mi++)
#pragma unroll
        for (int ni = 0; ni < 2; ni++)
#pragma unroll
            for (int r = 0; r < 4; r++) {
                if (isQ) {
                    int m = m0 + wr * 64 + mi * 16 + lg * 4 + r;
                    int n = n0 + wc * 32 + ni * 16 + lr;
                    int h = n >> 6, d = n & 63;
                    int b = m >> 11, lq = m & 2047;
                    Qh[((((size_t)b * NH + h) * NLQ + lq) << 6) + d] =
                        f2bf((acc[mi][ni][r] + bq[n]) * QSC);
                } else if (!isV) {
                    int m = m0 + wr * 64 + mi * 16 + lg * 4 + r;
                    int n = n0 + wc * 32 + ni * 16 + lr;
                    int h = n >> 6, d = n & 63;
                    int b = m >> 12, lkv = m & 4095;
                    Kh[((((size_t)b * NH + h) * NLKV + lkv) << 6) + d] =
                        f2bf(acc[mi][ni][r] + bk[n]);
                } else {
                    // transposed acc: row = n2 (d-dim), col = m (lkv, 16 consecutive)
                    int n2 = (n0 - 1024) + wc * 32 + ni * 16 + lg * 4 + r;
                    int m = m0 + wr * 64 + mi * 16 + lr;
                    int h = n2 >> 6, d = n2 & 63;
                    int b = m >> 12, lkv = m & 4095;
                    float val = vmask[(size_t)b * NLKV + lkv]
                                    ? acc[mi][ni][r] + bv[n2] : 0.f;
                    VTh[(((size_t)b * NH + h) * NHD + d) * NLKV + lkv] = f2bf(val);
                }
            }
}

// ---------- O-projection GEMM (f32 out), 64x128 tile -> 512 blocks (2/CU) ----------
// 256 thr = 4 waves 2x2; wave tile 32x64 (acc[2][4]). GL16 staging, BK=32.
__global__ __launch_bounds__(256) void ogemm_kernel(
    const u16* __restrict__ A, const u16* __restrict__ Bt,
    const float* __restrict__ bias, float* __restrict__ Cout) {
    __shared__ __align__(16) u16 As[64 * 32];
    __shared__ __align__(16) u16 Bs[128 * 32];
    const int m0 = blockIdx.x * 64;
    const int n0 = blockIdx.y * 128;
    const int tid = threadIdx.x;
    const int lane = tid & 63, w = tid >> 6;
    const int wr = w >> 1, wc = w & 1;  // 2x2 wave grid
    const int lr = lane & 15, lg = lane >> 4;
    const int ko = lg * 8;

    f32x4 acc[2][4];
#pragma unroll
    for (int i = 0; i < 2; i++)
#pragma unroll
        for (int j = 0; j < 4; j++)
#pragma unroll
            for (int r = 0; r < 4; r++) acc[i][j][r] = 0.f;

    const int srow = tid >> 2, spart = tid & 3;
    const u16* Ag = A + (size_t)(m0 + srow) * ND + spart * 8;
    const u16* Bg = Bt + (size_t)(n0 + srow) * ND + spart * 8;
    const u16* Bg2 = Bt + (size_t)(n0 + 64 + srow) * ND + spart * 8;
    u16* lA = &As[w * 512];
    u16* lB = &Bs[w * 512];
    u16* lB2 = &Bs[2048 + w * 512];

    for (int kt = 0; kt < ND; kt += 32) {
        GL16(Ag + kt, lA);
        GL16(Bg + kt, lB);
        GL16(Bg2 + kt, lB2);
        __syncthreads();

        s16x8 af[2], bf[4];
#pragma unroll
        for (int i = 0; i < 2; i++)
            af[i] = *(const s16x8*)&As[(wr * 32 + i * 16 + lr) * 32 + ko];
#pragma unroll
        for (int j = 0; j < 4; j++)
            bf[j] = *(const s16x8*)&Bs[(wc * 64 + j * 16 + lr) * 32 + ko];
#pragma unroll
        for (int mi = 0; mi < 2; mi++)
#pragma unroll
            for (int ni = 0; ni < 4; ni++)
                acc[mi][ni] = __builtin_amdgcn_mfma_f32_16x16x32_bf16(
                    af[mi], bf[ni], acc[mi][ni], 0, 0, 0);
        __syncthreads();
    }

#pragma unroll
    for (int mi = 0; mi < 2; mi++)
#pragma unroll
        for (int ni = 0; ni < 4; ni++)
#pragma unroll
            for (int r = 0; r < 4; r++) {
                int m = m0 + wr * 32 + mi * 16 + lg * 4 + r;
                int n = n0 + wc * 64 + ni * 16 + lr;
                Cout[(size_t)m * ND + n] = acc[mi][ni][r] + bias[n];
            }
}

// ---------- flash attention (R14 body, unsplit) + T5 setprio ----------
// grid (16, 32). l = bx + 16*by; bh = (l&7)*4 + ((l>>3)&3), qt = l>>5 (XCD
// bh-locality: FETCH 135->20.5MB, R13). Full-rank swizzle (row&7)^((row>>3)&3)
// (conflicts 8.5M->~200K, R14). s_setprio(1) wraps the MFMA clusters (T5,
// m191: +4-7% attn in the independent-wave regime).
__global__ __launch_bounds__(256) void attn_kernel(
    const u16* __restrict__ Qh, const u16* __restrict__ Kh,
    const u16* __restrict__ VTh, const u16* __restrict__ mbf,
    u16* __restrict__ attn) {
    const int l = blockIdx.x + 16 * blockIdx.y;
    const int qt = l >> 5;
    const int bh = (l & 7) * 4 + ((l >> 3) & 3);
    const int b = bh >> 4, h = bh & 15;
    const int tid = threadIdx.x;
    const int lane = tid & 63, w = tid >> 6;
    const int c = lane & 31, hi = lane >> 5;
    const int c7 = c & 7, c3 = (c >> 3) & 3;

    __shared__ __align__(16) u16 kt[2][4096];
    __shared__ __align__(16) u16 vt[2][4096];

    const int qw0 = qt * 128 + w * 32;
    const u16* Qb = Qh + (size_t)bh * NLQ * NHD;
    const u16* Kb = Kh + (size_t)bh * NLKV * NHD;
    const u16* VTb = VTh + (size_t)bh * NHD * NLKV;
    const u16* mbfb = mbf + (size_t)b * NLKV;

    // Q B-fragments: lane holds Q[qw0+c][kb*16 + hi*8 .. +7]
    s16x8 qa[4];
#pragma unroll
    for (int kb = 0; kb < 4; kb++)
        qa[kb] = *(const s16x8*)(Qb + (size_t)(qw0 + c) * NHD + kb * 16 + hi * 8);

    f32x16 o0, o1, lacc;
#pragma unroll
    for (int r = 0; r < 16; r++) { o0[r] = 0.f; o1[r] = 0.f; lacc[r] = 0.f; }

    // staging: row srow & srow+32, chunk sj; slot j holds logical chunk
    // j ^ (row&7) ^ ((row>>3)&3)   (key(row+32) == key(row))
    const int srow = 8 * w + (lane >> 3);
    const int sj = lane & 7;
    const int sx8 = (sj ^ (srow & 7) ^ ((srow >> 3) & 3)) * 8;
    const u16* kS1 = Kb + (size_t)srow * NHD + sx8;
    const u16* kS2 = Kb + (size_t)(srow + 32) * NHD + sx8;
    const u16* vS1 = VTb + (size_t)srow * NLKV + sx8;
    const u16* vS2 = VTb + (size_t)(srow + 32) * NLKV + sx8;
    const int d1 = w * 512, d2 = 2048 + w * 512;

    // prologue: stage tile 0 into buffer 0
    GL16(kS1, &kt[0][d1]);
    GL16(kS2, &kt[0][d2]);
    GL16(vS1, &vt[0][d1]);
    GL16(vS2, &vt[0][d2]);

    const int NT = NLKV / 64;
    for (int t = 0; t < NT; t++) {
        const int cur = t & 1;
        __syncthreads();  // buf[cur] staged (vmcnt drained) + buf[cur^1] free
        if (t + 1 < NT) {
            size_t kvo = (size_t)(t + 1) * 64;
            GL16(kS1 + kvo * NHD, &kt[cur ^ 1][d1]);
            GL16(kS2 + kvo * NHD, &kt[cur ^ 1][d2]);
            GL16(vS1 + kvo, &vt[cur ^ 1][d1]);
            GL16(vS2 + kvo, &vt[cur ^ 1][d2]);
        }
        // mask A-fragments (broadcast rows)
        s16x8 mf[4];
#pragma unroll
        for (int pb = 0; pb < 4; pb++)
            mf[pb] = *(const s16x8*)(mbfb + t * 64 + pb * 16 + hi * 8);

        const u16* ktc = kt[cur];
        const u16* vtc = vt[cur];

        // QK^T swapped: s0 = S^T rows kv 0..31, s1 = rows 32..63; col q = c
        f32x16 s0, s1;
#pragma unroll
        for (int r = 0; r < 16; r++) { s0[r] = 0.f; s1[r] = 0.f; }
        __builtin_amdgcn_s_setprio(1);
#pragma unroll
        for (int kb = 0; kb < 4; kb++) {
            int slot = ((kb * 2 + hi) ^ c7 ^ c3) << 3;
            s16x8 kf0 = *(const s16x8*)&ktc[c * 64 + slot];
            s16x8 kf1 = *(const s16x8*)&ktc[(32 + c) * 64 + slot];
            s0 = __builtin_amdgcn_mfma_f32_32x32x16_bf16(kf0, qa[kb], s0, 0, 0, 0);
            s1 = __builtin_amdgcn_mfma_f32_32x32x16_bf16(kf1, qa[kb], s1, 0, 0, 0);
        }
        __builtin_amdgcn_s_setprio(0);

        // softmax: pure exp2 (Q pre-scaled; mask via V-zeroing + l-MFMA)
        float p0a[16], p1a[16];
#pragma unroll
        for (int r = 0; r < 16; r++) {
            p0a[r] = fast_exp2(s0[r]);
            p1a[r] = fast_exp2(s1[r]);
        }

        // pack to bf16 pairs + permlane swap -> PV B-fragments
        u32 pka[8], pkb2[8];
#pragma unroll
        for (int i = 0; i < 8; i++) {
            pka[i] = pkbf(p0a[2 * i], p0a[2 * i + 1]);
            pkb2[i] = pkbf(p1a[2 * i], p1a[2 * i + 1]);
        }
        pl32swap(pka[0], pka[2]); pl32swap(pka[1], pka[3]);
        pl32swap(pka[4], pka[6]); pl32swap(pka[5], pka[7]);
        pl32swap(pkb2[0], pkb2[2]); pl32swap(pkb2[1], pkb2[3]);
        pl32swap(pkb2[4], pkb2[6]); pl32swap(pkb2[5], pkb2[7]);

        union { u32 u[4]; s16x8 h; } fr[4];
#pragma unroll
        for (int i = 0; i < 4; i++) {
            fr[0].u[i] = pka[i];
            fr[1].u[i] = pka[4 + i];
            fr[2].u[i] = pkb2[i];
            fr[3].u[i] = pkb2[4 + i];
        }

        // PV: O^T[d][q=c] += V^T[d][kv] * P ; l via mask-MFMA on same P frags
        __builtin_amdgcn_s_setprio(1);
#pragma unroll
        for (int pb = 0; pb < 4; pb++) {
            int slot = ((pb * 2 + hi) ^ c7 ^ c3) << 3;
            s16x8 vf0 = *(const s16x8*)&vtc[c * 64 + slot];
            s16x8 vf1 = *(const s16x8*)&vtc[(32 + c) * 64 + slot];
            o0 = __builtin_amdgcn_mfma_f32_32x32x16_bf16(vf0, fr[pb].h, o0, 0, 0, 0);
            o1 = __builtin_amdgcn_mfma_f32_32x32x16_bf16(vf1, fr[pb].h, o1, 0, 0, 0);
            lacc = __builtin_amdgcn_mfma_f32_32x32x16_bf16(mf[pb], fr[pb].h, lacc, 0, 0, 0);
        }
        __builtin_amdgcn_s_setprio(0);
    }

    // lacc rows are all identical = l[q=c] over the full kv range
    float linv = 1.f / lacc[0];

    // epilogue: transpose O through LDS (reuse kt), coalesced global write.
    __syncthreads();
    u32* osh = (u32*)kt + w * 1024;  // per-wave [32 rows][32 dwords]
#pragma unroll
    for (int r = 0; r < 16; r += 2) {
        int d = (r & 3) + 8 * (r >> 2) + 4 * hi;
        u32 plo = pkbf(o0[r] * linv, o0[r + 1] * linv);
        u32 phi = pkbf(o1[r] * linv, o1[r + 1] * linv);
        int dc0 = d >> 1, dc1 = (d + 32) >> 1;
        osh[c * 32 + (((dc0 >> 2) ^ c7) << 2) + (dc0 & 3)] = plo;
        osh[c * 32 + (((dc1 >> 2) ^ c7) << 2) + (dc1 & 3)] = phi;
    }
    __syncthreads();
#pragma unroll
    for (int i = 0; i < 4; i++) {
        int row = 8 * i + (lane >> 3);
        int jj = lane & 7;
        u32 v0 = osh[row * 32 + ((jj ^ (row & 7)) << 2) + 0];
        u32 v1 = osh[row * 32 + ((jj ^ (row & 7)) << 2) + 1];
        u32 v2 = osh[row * 32 + ((jj ^ (row & 7)) << 2) + 2];
        u32 v3 = osh[row * 32 + ((jj ^ (row & 7)) << 2) + 3];
        u32* gp = (u32*)(attn + ((size_t)b * NLQ + qw0 + row) * ND + h * NHD + jj * 8);
        gp[0] = v0; gp[1] = v1; gp[2] = v2; gp[3] = v3;
    }
}

extern "C" void kernel_launch(void* const* d_in, const int* in_sizes, int n_in,
                              void* d_out, int out_size, void* d_ws, size_t ws_size,
                              hipStream_t stream) {
    const float* x_q = (const float*)d_in[0];
    const float* x_kv = (const float*)d_in[1];
    const int* mask = (const int*)d_in[2];
    const float* Wq = (const float*)d_in[3];
    const float* bq = (const float*)d_in[4];
    const float* Wk = (const float*)d_in[5];
    const float* bk = (const float*)d_in[6];
    const float* Wv = (const float*)d_in[7];
    const float* bv = (const float*)d_in[8];
    const float* Wo = (const float*)d_in[9];
    const float* bo = (const float*)d_in[10];
    float* out = (float*)d_out;

    size_t off = 0;
    auto carve = [&](size_t bytes) {
        void* p = (char*)d_ws + off;
        off += (bytes + 255) & ~(size_t)255;
        return p;
    };
    u16* xq_bf = (u16*)carve((size_t)NB * NLQ * ND * 2);
    u16* xkv_bf = (u16*)carve((size_t)NB * NLKV * ND * 2);
    u16* wq_t = (u16*)carve((size_t)ND * ND * 2);
    u16* wkv_t = (u16*)carve((size_t)2 * ND * ND * 2);
    u16* wo_t = (u16*)carve((size_t)ND * ND * 2);
    u16* Qh = (u16*)carve((size_t)NB * NH * NLQ * NHD * 2);
    u16* Kh = (u16*)carve((size_t)NB * NH * NLKV * NHD * 2);
    u16* VTh = (u16*)carve((size_t)NB * NH * NLKV * NHD * 2);
    u16* attn_bf = (u16*)carve((size_t)NB * NLQ * ND * 2);
    u16* mbfw = (u16*)carve((size_t)NB * NLKV * 2);

    cvt2_kernel<<<dim3(6176), 256, 0, stream>>>(x_q, x_kv, mask, xq_bf, xkv_bf, mbfw);
    tcvt_kernel<<<dim3(32, 32, 4), dim3(32, 8), 0, stream>>>(
        Wq, Wk, Wv, Wo, wq_t, wkv_t, wkv_t + (size_t)ND * ND, wo_t);
    qkv_kernel<<<dim3(1280), 512, 0, stream>>>(xq_bf, xkv_bf, wq_t, wkv_t,
                                               bq, bk, bv, mask, Qh, Kh, VTh);
    attn_kernel<<<dim3(16, 32), 256, 0, stream>>>(Qh, Kh, VTh, mbfw, attn_bf);
    ogemm_kernel<<<dim3(64, 8), 256, 0, stream>>>(attn_bf, wo_t, bo, out);
}